// Round 10
// baseline (357.126 us; speedup 1.0000x reference)
//
#include <hip/hip_runtime.h>
#include <stdint.h>

// ---------------------------------------------------------------------------
// DkNN round 14: Bh eliminated — X->bf16 conversion fused into mfma_tile's
// B-staging (reg-stage: float4 loads -> bf16_rn -> swizzled ds_write_b128),
// keeping the verified 33KB-LDS / 4-blocks-per-CU / 2-barrier structure.
//  - prep_q: query side only (verified R7/R11 kernel).
//  - mfma_tile: per K-step, waves 0,1 gload_lds the A slice (unchanged);
//    ALL threads convert the B slice from X (thread = row tid>>1, 32 dims).
//    Row norms accumulate in registers across the 4 steps; m_t==0 blocks
//    publish xn2[ntile..] and pmax[n_t]. Epilogue reads norms from LDS.
//    XCD swizzle keeps the 8 m-blocks of an n-tile on one XCD -> X re-reads
//    hit that XCD's L2 (FETCH_SIZE is the verdict counter).
//  - select_classify: R9-verified; pmax array is now per-n-tile (ntiles).
// ---------------------------------------------------------------------------

typedef __attribute__((ext_vector_type(8))) short short8;   // 8 bf16 = 4 VGPR
typedef __attribute__((ext_vector_type(4))) float float4v;  // MFMA C/D

static __device__ __forceinline__ unsigned short bf16_rn(float f) {
    unsigned int u = __float_as_uint(f);
    unsigned int r = (u + 0x7FFFu + ((u >> 16) & 1u)) >> 16;
    return (unsigned short)r;
}

static __device__ __forceinline__ void gload_lds16(const void* g, void* l) {
    __builtin_amdgcn_global_load_lds(
        (const __attribute__((address_space(1))) unsigned int*)g,
        (__attribute__((address_space(3))) unsigned int*)l, 16, 0, 0);
}

// One block per query row: normalize, center, bf16-hi split, norms.
__global__ __launch_bounds__(256) void prep_q(
    const float* __restrict__ x, const float* __restrict__ center,
    unsigned short* __restrict__ Ah, float* __restrict__ xqf,
    float* __restrict__ q2a, float* __restrict__ al2q, int B, int Mp)
{
    const int tid = threadIdx.x;
    const int row = blockIdx.x;
    __shared__ float p1[4], p2[4], p3[4];
    if (row >= Mp) return;
    if (row >= B) {
        Ah[(size_t)row * 256 + tid] = 0;
        xqf[(size_t)row * 256 + tid] = 0.f;
        if (tid == 0) { q2a[row] = 0.f; al2q[row] = 0.f; }
        return;
    }
    float v = x[(size_t)row * 256 + tid];
    float ss = v * v;
    #pragma unroll
    for (int s = 1; s < 64; s <<= 1) ss += __shfl_xor(ss, s);
    if ((tid & 63) == 0) p1[tid >> 6] = ss;
    __syncthreads();
    float tot = p1[0] + p1[1] + p1[2] + p1[3];
    float inv = 1.0f / sqrtf(tot);
    float val = v * inv - center[tid];
    unsigned short hb = bf16_rn(val);
    float hf = __uint_as_float((unsigned int)hb << 16);
    float al = val - hf;
    Ah[(size_t)row * 256 + tid] = hb;
    xqf[(size_t)row * 256 + tid] = val;
    float ss2 = val * val, sal = al * al;
    #pragma unroll
    for (int s = 1; s < 64; s <<= 1) {
        ss2 += __shfl_xor(ss2, s);
        sal += __shfl_xor(sal, s);
    }
    if ((tid & 63) == 0) { p2[tid >> 6] = ss2; p3[tid >> 6] = sal; }
    __syncthreads();
    if (tid == 0) {
        q2a[row]  = p2[0] + p2[1] + p2[2] + p2[3];
        al2q[row] = p3[0] + p3[1] + p3[2] + p3[3];
    }
}

// 128x128 tile, 4 waves each computing a 64x64 quadrant (4x4 frags of 16x16x32).
// Single pass Ah * bf16(X), 4 K-steps of BK=64. B converted from fp32 X into
// swizzled LDS each step; A gload_lds'd (unchanged). Epilogue: per-(query,
// 64-col group) min of xn2 - 2*dot -> gmin.
__global__ __launch_bounds__(256, 4) void mfma_tile(
    const unsigned short* __restrict__ Ah,   // Mp*256 bf16
    const float* __restrict__ X,             // nb_train*256 f32
    float* __restrict__ xn2,                 // Np (written by m_t==0 blocks)
    float* __restrict__ pmax,                // ntiles (written by m_t==0 blocks)
    float* __restrict__ gmin,
    int Mp, int Np, int nb_train, int B,
    int ntiles, int nper, int mtiles)
{
    __shared__ unsigned short As[128 * 64];   // [row][chunk ^ (row&7)] 16B chunks
    __shared__ unsigned short Bs[128 * 64];
    __shared__ float xnl[128];
    __shared__ float sm4[4];

    const int bid = blockIdx.x;
    const int xcd = bid & 7;
    const int s_  = bid >> 3;
    const int n_t = xcd * nper + (s_ / mtiles);
    const int m_t = s_ - (s_ / mtiles) * mtiles;
    if (n_t >= ntiles) return;
    const int mtile = m_t * 128;
    const int ntile = n_t * 128;

    const int tid  = threadIdx.x;
    const int wave = tid >> 6;
    const int lane = tid & 63;

    // ---- A staging (waves 0,1): rows [0:64),[64:128), 8 gloads each thread
    const int Rwave  = (wave & 1) * 64;
    const int lrow8  = lane >> 3;
    const int lchunk = lane & 7;
    const unsigned short* sbaseA =
        Ah + (size_t)(mtile + Rwave + lrow8) * 256 + (size_t)((lchunk ^ lrow8) * 8);
    unsigned short* lwaveA = As + Rwave * 64;

    // ---- B conversion: thread = row (tid>>1), 32-dim half (tid&1) of 64-slice
    const int brow = tid >> 1;
    const int bh   = tid & 1;
    const bool bok = (ntile + brow) < nb_train;
    const float* bsrc = X + (size_t)(ntile + brow) * 256 + bh * 32;
    const int bsw = brow & 7;
    unsigned short* brp = Bs + brow * 64;
    float bss = 0.f;

    // ---- compute role: quadrant
    const int mq = (wave >> 1) * 64;
    const int nq = (wave & 1) * 64;
    const int lrow = lane & 15;
    const int kseg = lane >> 4;
    const int sw = lrow & 7;

    float4v acc[4][4];
    #pragma unroll
    for (int i = 0; i < 4; ++i)
        #pragma unroll
        for (int j = 0; j < 4; ++j)
            acc[i][j] = (float4v){0.f, 0.f, 0.f, 0.f};

    for (int s = 0; s < 4; ++s) {
        __syncthreads();   // previous step's compute done before overwrite
        if (wave < 2) {
            const unsigned short* g = sbaseA + (size_t)(s * 64);
            #pragma unroll
            for (int q = 0; q < 8; ++q)
                gload_lds16(g + q * 2048, lwaveA + q * 512);
        }
        // B: convert 32 floats (2 batches of 16 to bound register pressure)
        const float* srcs = bsrc + s * 64;
        #pragma unroll
        for (int hb = 0; hb < 2; ++hb) {
            short8 c0, c1;
            if (bok) {
                const float4* sp = (const float4*)(srcs + hb * 16);
                float4 f0 = sp[0], f1 = sp[1], f2 = sp[2], f3 = sp[3];
                c0[0] = (short)bf16_rn(f0.x); c0[1] = (short)bf16_rn(f0.y);
                c0[2] = (short)bf16_rn(f0.z); c0[3] = (short)bf16_rn(f0.w);
                c0[4] = (short)bf16_rn(f1.x); c0[5] = (short)bf16_rn(f1.y);
                c0[6] = (short)bf16_rn(f1.z); c0[7] = (short)bf16_rn(f1.w);
                c1[0] = (short)bf16_rn(f2.x); c1[1] = (short)bf16_rn(f2.y);
                c1[2] = (short)bf16_rn(f2.z); c1[3] = (short)bf16_rn(f2.w);
                c1[4] = (short)bf16_rn(f3.x); c1[5] = (short)bf16_rn(f3.y);
                c1[6] = (short)bf16_rn(f3.z); c1[7] = (short)bf16_rn(f3.w);
                bss += f0.x * f0.x + f0.y * f0.y + f0.z * f0.z + f0.w * f0.w
                     + f1.x * f1.x + f1.y * f1.y + f1.z * f1.z + f1.w * f1.w
                     + f2.x * f2.x + f2.y * f2.y + f2.z * f2.z + f2.w * f2.w
                     + f3.x * f3.x + f3.y * f3.y + f3.z * f3.z + f3.w * f3.w;
            } else {
                c0 = (short8){0, 0, 0, 0, 0, 0, 0, 0};
                c1 = c0;
            }
            const int cA = bh * 4 + hb * 2;
            *(short8*)&brp[(cA ^ bsw) * 8]       = c0;
            *(short8*)&brp[((cA + 1) ^ bsw) * 8] = c1;
        }
        __syncthreads();   // staging complete (vmcnt + lgkmcnt drain + barrier)
        #pragma unroll
        for (int t = 0; t < 2; ++t) {
            const int wch = ((t * 4 + kseg) ^ sw) * 8;
            short8 a[4], b[4];
            #pragma unroll
            for (int i = 0; i < 4; ++i)
                a[i] = *(const short8*)&As[(mq + i * 16 + lrow) * 64 + wch];
            #pragma unroll
            for (int j = 0; j < 4; ++j)
                b[j] = *(const short8*)&Bs[(nq + j * 16 + lrow) * 64 + wch];
            #pragma unroll
            for (int i = 0; i < 4; ++i)
                #pragma unroll
                for (int j = 0; j < 4; ++j)
                    acc[i][j] = __builtin_amdgcn_mfma_f32_16x16x32_bf16(
                        a[i], b[j], acc[i][j], 0, 0, 0);
        }
    }

    // ---- finalize row norms (pair-combine the two 128-dim halves) ----
    float stot = bss + __shfl_xor(bss, 1);
    if (bh == 0) xnl[brow] = bok ? stot : 3.0e38f;
    float mx = (bh == 0 && bok) ? stot : 0.f;
    #pragma unroll
    for (int sft = 1; sft < 64; sft <<= 1) mx = fmaxf(mx, __shfl_xor(mx, sft));
    if (lane == 0) sm4[wave] = mx;
    __syncthreads();
    if (m_t == 0) {
        if (tid < 128) xn2[ntile + tid] = xnl[tid];
        if (tid == 0)
            pmax[n_t] = fmaxf(fmaxf(sm4[0], sm4[1]), fmaxf(sm4[2], sm4[3]));
    }

    // ---- epilogue: per-(q, 64-col group) min of xn2 - 2*dot ----
    const int ng64 = Np >> 6;
    const int gb = (ntile + nq) >> 6;       // this wave's group index
    float xnv[4];
    #pragma unroll
    for (int j = 0; j < 4; ++j)
        xnv[j] = xnl[nq + j * 16 + lrow];   // pads hold 3e38

    #pragma unroll
    for (int i = 0; i < 4; ++i) {
        #pragma unroll
        for (int r = 0; r < 4; ++r) {
            const int lm = mq + i * 16 + kseg * 4 + r;   // block-local query
            const int gq = mtile + lm;
            float vm = fminf(
                fminf(xnv[0] - 2.0f * acc[i][0][r], xnv[1] - 2.0f * acc[i][1][r]),
                fminf(xnv[2] - 2.0f * acc[i][2][r], xnv[3] - 2.0f * acc[i][3][r]));
            #pragma unroll
            for (int sft = 1; sft < 16; sft <<= 1)
                vm = fminf(vm, __shfl_xor(vm, sft));
            if (lrow == 0 && gq < B)
                gmin[(size_t)gq * ng64 + gb] = vm;
        }
    }
}

// One block per query: approx minima -> window from rigorous bound -> exact
// fp32 rescore of candidate 64-row groups -> fused conformal classification.
__global__ __launch_bounds__(256) void select_classify(
    const float* __restrict__ gmin, const float* __restrict__ xqf,
    const float* __restrict__ X, const float* __restrict__ xn2,
    const float* __restrict__ q2a, const float* __restrict__ al2q,
    const float* __restrict__ pmax,
    const int* __restrict__ labels, const int* __restrict__ nbr,
    const int* __restrict__ cali, float* __restrict__ out,
    int Np, int nb_train, int knm1, int nb_cali, int B, int npm)
{
    extern __shared__ float gbuf[];            // ng64 floats
    __shared__ float xq_s[256];
    __shared__ float wmin[4], wpm[4], fsc[4];
    __shared__ int   fid[4];
    __shared__ float s_thr;
    __shared__ int   cand[256];
    __shared__ int   s_ncand;
    __shared__ int   s_closest;

    const int q    = blockIdx.x;
    const int tid  = threadIdx.x;
    const int lane = tid & 63;
    const int wave = tid >> 6;
    const int ng64 = Np >> 6;

    if (tid == 0) s_ncand = 0;
    xq_s[tid] = xqf[(size_t)q * 256 + tid];
    float vmin = 3.4e38f;
    for (int i = tid; i < ng64; i += 256) {
        float v = gmin[(size_t)q * ng64 + i];
        gbuf[i] = v;
        vmin = fminf(vmin, v);
    }
    float pm = 0.f;
    for (int i = tid; i < npm; i += 256) pm = fmaxf(pm, pmax[i]);
    #pragma unroll
    for (int s = 1; s < 64; s <<= 1) {
        vmin = fminf(vmin, __shfl_xor(vmin, s));
        pm   = fmaxf(pm,   __shfl_xor(pm, s));
    }
    if (lane == 0) { wmin[wave] = vmin; wpm[wave] = pm; }
    __syncthreads();
    if (tid == 0) {
        float m = fminf(fminf(wmin[0], wmin[1]), fminf(wmin[2], wmin[3]));
        float mb2 = fmaxf(fmaxf(wpm[0], wpm[1]), fmaxf(wpm[2], wpm[3]));
        float maxb  = sqrtf(mb2);
        float maxbl = maxb * 0.00390625f;          // ||Bl|| <= 2^-8 ||B||, rigorous
        float an = sqrtf(q2a[q]), al = sqrtf(al2q[q]);
        float errdot = al * maxb * 1.00390625f + (an + al) * maxbl;
        s_thr = m + 4.0f * errdot + 1e-3f;
    }
    __syncthreads();
    const float thr = s_thr;
    for (int g = tid; g < ng64; g += 256) {
        if (gbuf[g] <= thr) {
            int p = atomicAdd(&s_ncand, 1);
            if (p < 256) cand[p] = g;
        }
    }
    __syncthreads();
    const int nc = s_ncand;

    // exact rescore: 4 lanes per row (dim quarters), 64 rows per group.
    const int rsub = tid & 3;
    const int rrow = tid >> 2;
    float bsc = 3.4e38f; int bidx = 0x7FFFFFFF;
    auto rescore = [&](int g) {
        int row = g * 64 + rrow;
        if (row < nb_train) {
            const float* xr = X + (size_t)row * 256 + rsub * 64;
            const float* xs = xq_s + rsub * 64;
            float dot = 0.f;
            #pragma unroll
            for (int k = 0; k < 16; ++k) {
                float4 a4 = *(const float4*)(xs + k * 4);
                float4 b4 = *(const float4*)(xr + k * 4);
                dot += a4.x * b4.x + a4.y * b4.y + a4.z * b4.z + a4.w * b4.w;
            }
            dot += __shfl_xor(dot, 1);
            dot += __shfl_xor(dot, 2);
            float sc = xn2[row] - 2.0f * dot;
            if (sc < bsc || (sc == bsc && row < bidx)) { bsc = sc; bidx = row; }
        }
    };
    if (nc <= 256) {
        for (int c = 0; c < nc; ++c) rescore(cand[c]);
    } else {
        for (int g = 0; g < ng64; ++g)
            if (gbuf[g] <= thr) rescore(g);      // correctness backstop
    }
    #pragma unroll
    for (int s = 1; s < 64; s <<= 1) {
        float osc = __shfl_xor(bsc, s);
        int   oid = __shfl_xor(bidx, s);
        if (osc < bsc || (osc == bsc && oid < bidx)) { bsc = osc; bidx = oid; }
    }
    if (lane == 0) { fsc[wave] = bsc; fid[wave] = bidx; }
    __syncthreads();
    if (tid == 0) {
        float bs = fsc[0]; int bi = fid[0];
        #pragma unroll
        for (int w = 1; w < 4; ++w)
            if (fsc[w] < bs || (fsc[w] == bs && fid[w] < bi)) { bs = fsc[w]; bi = fid[w]; }
        s_closest = bi;
    }
    __syncthreads();

    if (wave == 0) {
        const int closest = s_closest;
        const int K = knm1 + 1;   // 75
        int lbl0 = -1, lbl1 = -1;
        if (lane < K) {
            int idx = (lane == 0) ? closest : nbr[(size_t)closest * knm1 + (lane - 1)];
            lbl0 = labels[idx];
        }
        int j2 = lane + 64;
        if (j2 < K) {
            int idx = nbr[(size_t)closest * knm1 + (j2 - 1)];
            lbl1 = labels[idx];
        }
        int bestc = 0, bestp = -1;
        #pragma unroll
        for (int c = 0; c < 10; ++c) {
            int cnt = __popcll(__ballot(lbl0 == c)) + __popcll(__ballot(lbl1 == c));
            int v = K - cnt;
            int lo = 0, hi = nb_cali;
            while (lo < hi) {             // bisect_left
                int mid = (lo + hi) >> 1;
                if (cali[mid] < v) lo = mid + 1; else hi = mid;
            }
            int p = nb_cali - lo;
            if (p > bestp) { bestp = p; bestc = c; }
        }
        float pv = (float)bestp / (float)nb_cali;
        if (lane < 10)
            out[(size_t)q * 10 + lane] = (lane == bestc) ? pv : 0.0f;
    }
}

extern "C" void kernel_launch(void* const* d_in, const int* in_sizes, int n_in,
                              void* d_out, int out_size, void* d_ws, size_t ws_size,
                              hipStream_t stream) {
    const float* x      = (const float*)d_in[0];
    const float* X      = (const float*)d_in[1];
    const float* center = (const float*)d_in[2];
    const int* labels   = (const int*)d_in[3];
    const int* nbr      = (const int*)d_in[4];
    const int* cali     = (const int*)d_in[5];
    float* out = (float*)d_out;

    const int d        = in_sizes[2];              // 256
    const int B        = in_sizes[0] / d;          // 1024
    const int nb_train = in_sizes[3];              // 100000
    const int knm1     = in_sizes[4] / nb_train;   // 74
    const int nb_cali  = in_sizes[5];              // 1000

    const int Mp = (B + 127) & ~127;               // 1024
    const int Np = (nb_train + 127) & ~127;        // 100096
    const int ng64 = Np >> 6;                      // 1564
    const int ntiles = Np / 128;                   // 782
    const int mtiles = Mp / 128;                   // 8
    const int nper   = (ntiles + 7) / 8;           // 98

    char* ws = (char*)d_ws;
    size_t off = 0;
    float* gmin = (float*)(ws + off);          off += (size_t)Mp * ng64 * 4;
    unsigned short* Ah = (unsigned short*)(ws + off); off += (size_t)Mp * 256 * 2;
    float* xqf  = (float*)(ws + off);          off += (size_t)Mp * 256 * 4;
    float* q2a  = (float*)(ws + off);          off += (size_t)Mp * 4;
    float* al2q = (float*)(ws + off);          off += (size_t)Mp * 4;
    float* xn2  = (float*)(ws + off);          off += (size_t)Np * 4;
    float* pmax = (float*)(ws + off);          off += (size_t)ntiles * 4;

    prep_q<<<Mp, 256, 0, stream>>>(x, center, Ah, xqf, q2a, al2q, B, Mp);

    mfma_tile<<<8 * nper * mtiles, 256, 0, stream>>>(
        Ah, X, xn2, pmax, gmin, Mp, Np, nb_train, B, ntiles, nper, mtiles);

    select_classify<<<B, 256, ng64 * 4, stream>>>(
        gmin, xqf, X, xn2, q2a, al2q, pmax, labels, nbr, cali, out,
        Np, nb_train, knm1, nb_cali, B, ntiles);
}